// Round 8
// baseline (217.436 us; speedup 1.0000x reference)
//
#include <hip/hip_runtime.h>
#include <cstdint>

// ---------------------------------------------------------------------------
// RotationScan: theta/retain/inp GEMM -> chunked complex scan -> out GEMM -> LN
// B=4 T=4096 D=1024 SD=512 CHUNK=32
// ---------------------------------------------------------------------------

typedef __bf16 bf16x8 __attribute__((ext_vector_type(8)));
typedef float  f32x4  __attribute__((ext_vector_type(4)));
typedef ushort u16x8  __attribute__((ext_vector_type(8)));

#define AS1 __attribute__((address_space(1)))
#define AS3 __attribute__((address_space(3)))

__device__ __forceinline__ void gload16(const void* g, void* l) {
  __builtin_amdgcn_global_load_lds((const AS1 void*)g, (AS3 void*)l, 16, 0, 0);
}

__device__ __forceinline__ ushort f2bf(float f) {
  union { float f; uint32_t u; } v; v.f = f;
  uint32_t u = v.u;
  uint32_t r = u + 0x7FFFu + ((u >> 16) & 1u);   // RNE
  return (ushort)(r >> 16);
}
__device__ __forceinline__ float bf2f(ushort u) {
  union { uint32_t x; float f; } v; v.x = (uint32_t)u << 16; return v.f;
}

// ---------------------------------------------------------------------------
// Transpose + f32->bf16 convert:  dst[(row_off + c)*R + r] = bf16(src[r*C + c])
// ---------------------------------------------------------------------------
__global__ __launch_bounds__(256) void tconv(const float* __restrict__ src, int R, int C,
                                             ushort* __restrict__ dst, int row_off) {
  __shared__ float tile[32][33];
  int tx = threadIdx.x, ty = threadIdx.y;
  int rb = blockIdx.y * 32, cb = blockIdx.x * 32;
#pragma unroll
  for (int yy = 0; yy < 4; ++yy) {
    int r = rb + ty + yy * 8;
    tile[ty + yy * 8][tx] = src[(size_t)r * C + cb + tx];
  }
  __syncthreads();
#pragma unroll
  for (int yy = 0; yy < 4; ++yy) {
    int c = cb + ty + yy * 8;
    dst[(size_t)(row_off + c) * R + rb + tx] = f2bf(tile[tx][ty + yy * 8]);
  }
}

__global__ __launch_bounds__(256) void pack_bias(const float* __restrict__ bt,
                                                 const float* __restrict__ br,
                                                 const float* __restrict__ bi,
                                                 float* __restrict__ bcat) {
  int i = blockIdx.x * 256 + threadIdx.x;          // 0..2047
  bcat[i] = (i < 512) ? bt[i] : (i < 1024 ? br[i - 512] : bi[i - 1024]);
}

__global__ __launch_bounds__(256) void xconv(const float4* __restrict__ src,
                                             ushort* __restrict__ dst, int n4) {
  int i = blockIdx.x * 256 + threadIdx.x;
  if (i < n4) {
    float4 v = src[i];
    ushort4 o;
    o.x = f2bf(v.x); o.y = f2bf(v.y); o.z = f2bf(v.z); o.w = f2bf(v.w);
    *(ushort4*)(dst + (size_t)i * 4) = o;
  }
}

// ---------------------------------------------------------------------------
// BM x 256 tile (BM = 256 or 128), BK=64, 8 waves (2Mx4N), double-buffered LDS.
// m201-style per-phase barrier pairs: each phase = {ds_read frags, stage,
// [vmcnt], barrier, setprio+MFMA+setprio, barrier}. 8 barriers/K-tile.
//
// Stagger (race-audited for the 2-buffer layout):
//  ph0: read bF(all)+aF rg-pair0; STAGE A(kt+1)->As[nxt]
//       (As[nxt] reads sealed at kt-1.ph3 closing barrier)
//  ph1: aF rg-pair1; STAGE B_lo(kt+2)->Bs[cur]
//       (ALL bF reads of kt completed before ph0's closing barrier)
//  ph2: aF rg-pair2; STAGE B_hi(kt+2)->Bs[cur]
//  ph3: aF rg-pair3; vmcnt(4): leaves exactly B(kt+2)'s 4 loads outstanding,
//       forcing A(kt+1) (issued ph0, 3-phase slack) and B(kt+1) (issued
//       kt-1.ph1/2) landed; barrier then publishes to all waves.
//       Tail: kt==NKT-2 -> vmcnt(0); kt==NKT-1 -> none.
// Prologue: B(0), A(0), B(1); vmcnt(4) (B(1) stays in flight); barrier.
// Every vmcnt precedes a barrier shared by all waves -> cross-wave RAW holds.
//
// Epilogue (r7-verified): C-tile -> LDS with 16B-chunk XOR swizzle, then
// coalesced u16x8 stores (full 64B lines; WRITE_SIZE == output bytes).
// ---------------------------------------------------------------------------
template <int BM>
__global__ __launch_bounds__(512, 2) void gemm256(const ushort* __restrict__ A,
                                                  const ushort* __restrict__ Bt,
                                                  ushort* __restrict__ C,
                                                  const float* __restrict__ bias,
                                                  int M, int N, int K, int nbn) {
  constexpr int MI = BM / 32;            // acc row-groups per wave (8 or 4)
  constexpr int II = BM / 128;           // row-groups per phase (2 or 1)
  constexpr int STAGE_USH = 2 * (BM * 64 + 256 * 64);
  constexpr int CT_USH = BM * 256;
  constexpr int SM_USH = (STAGE_USH > CT_USH) ? STAGE_USH : CT_USH;
  __shared__ alignas(16) ushort smem[SM_USH];
  ushort* const As0 = smem;                       // As(buf) = As0 + buf*BM*64
  ushort* const Bs0 = smem + 2 * BM * 64;         // Bs(buf) = Bs0 + buf*256*64

  const int cpx = gridDim.x >> 3;
  const int wg = ((int)blockIdx.x & 7) * cpx + ((int)blockIdx.x >> 3);
  const int bm = wg / nbn, bn = wg % nbn;

  const int t = threadIdx.x;
  const int l = t & 63, w = t >> 6;
  const int wm = w >> 2, wn = w & 3;              // wave grid 2(M) x 4(N)
  const int r = l & 15, kq = l >> 4;

  const size_t a0 = (size_t)bm * BM * K;
  const size_t b0 = (size_t)bn * 256 * K;

  const int srow = t >> 3;                        // 0..63
  const int sslot = (t & 7) ^ (srow & 7);
  const ushort* gA = A + a0 + (size_t)srow * K + sslot * 8;
  const ushort* gB = Bt + b0 + (size_t)srow * K + sslot * 8;
  const int lboff = w * 1024 + l * 16;            // LDS byte offset in a pass

  f32x4 acc[MI][4] = {};
  const int NKT = K >> 6;

#define STGA(buf, kt, u) \
  gload16(gA + (size_t)((u) * 64) * K + (size_t)(kt) * 64, \
          (char*)(As0 + (buf) * BM * 64) + (u) * 8192 + lboff)
#define STGB(buf, kt, u) \
  gload16(gB + (size_t)((u) * 64) * K + (size_t)(kt) * 64, \
          (char*)(Bs0 + (buf) * 256 * 64) + (u) * 8192 + lboff)

  // PHASE for ph>=1 (aF only; bF already in regs). Order: ds_read, stage,
  // wait, clobber, barrier, MFMA cluster, clobber, barrier.
#define PHASE(ph, STAGE_STMT, WAIT_STMT)                                       \
  {                                                                            \
    bf16x8 aF[II][2];                                                          \
    _Pragma("unroll")                                                          \
    for (int ii = 0; ii < II; ++ii) {                                          \
      const int rowa = wm * (BM / 2) + ((ph) * II + ii) * 16 + r;              \
      _Pragma("unroll")                                                        \
      for (int ks = 0; ks < 2; ++ks) {                                         \
        const int j = (ks * 4 + kq) ^ (r & 7);                                 \
        aF[ii][ks] = *(const bf16x8*)&pA[rowa * 64 + j * 8];                   \
      }                                                                        \
    }                                                                          \
    STAGE_STMT;                                                                \
    WAIT_STMT;                                                                 \
    asm volatile("" ::: "memory");                                             \
    __builtin_amdgcn_s_barrier();                                              \
    __builtin_amdgcn_s_setprio(1);                                             \
    _Pragma("unroll")                                                          \
    for (int ii = 0; ii < II; ++ii)                                            \
      _Pragma("unroll")                                                        \
      for (int jn = 0; jn < 4; ++jn)                                           \
        _Pragma("unroll")                                                      \
        for (int ks = 0; ks < 2; ++ks)                                         \
          acc[(ph) * II + ii][jn] = __builtin_amdgcn_mfma_f32_16x16x32_bf16(   \
              aF[ii][ks], bF[jn][ks], acc[(ph) * II + ii][jn], 0, 0, 0);       \
    __builtin_amdgcn_s_setprio(0);                                             \
    asm volatile("" ::: "memory");                                             \
    __builtin_amdgcn_s_barrier();                                              \
  }

  // prologue: B(0), A(0), B(1); vmcnt(4) keeps B(1) in flight
  STGB(0, 0, 0); STGB(0, 0, 1); STGB(0, 0, 2); STGB(0, 0, 3);
  STGA(0, 0, 0); STGA(0, 0, 1);
  if constexpr (BM == 256) { STGA(0, 0, 2); STGA(0, 0, 3); }
  STGB(1, 1, 0); STGB(1, 1, 1); STGB(1, 1, 2); STGB(1, 1, 3);
  asm volatile("s_waitcnt vmcnt(4)" ::: "memory");
  __builtin_amdgcn_s_barrier();

  for (int kt = 0; kt < NKT; ++kt) {
    const int cur = kt & 1, nxt = cur ^ 1;
    const ushort* pA = As0 + cur * BM * 64;
    const ushort* pB = Bs0 + cur * 256 * 64;
    bf16x8 bF[4][2];
    // ===== phase 0: bF(all) + aF pair0; stage A(kt+1) -> As[nxt] =====
    {
#pragma unroll
      for (int jn = 0; jn < 4; ++jn) {
        const int rowb = wn * 64 + jn * 16 + r;
#pragma unroll
        for (int ks = 0; ks < 2; ++ks) {
          const int j = (ks * 4 + kq) ^ (r & 7);
          bF[jn][ks] = *(const bf16x8*)&pB[rowb * 64 + j * 8];
        }
      }
      bf16x8 aF[II][2];
#pragma unroll
      for (int ii = 0; ii < II; ++ii) {
        const int rowa = wm * (BM / 2) + ii * 16 + r;
#pragma unroll
        for (int ks = 0; ks < 2; ++ks) {
          const int j = (ks * 4 + kq) ^ (r & 7);
          aF[ii][ks] = *(const bf16x8*)&pA[rowa * 64 + j * 8];
        }
      }
      if (kt + 1 < NKT) {
        STGA(nxt, kt + 1, 0); STGA(nxt, kt + 1, 1);
        if constexpr (BM == 256) { STGA(nxt, kt + 1, 2); STGA(nxt, kt + 1, 3); }
      }
      asm volatile("" ::: "memory");
      __builtin_amdgcn_s_barrier();
      __builtin_amdgcn_s_setprio(1);
#pragma unroll
      for (int ii = 0; ii < II; ++ii)
#pragma unroll
        for (int jn = 0; jn < 4; ++jn)
#pragma unroll
          for (int ks = 0; ks < 2; ++ks)
            acc[ii][jn] = __builtin_amdgcn_mfma_f32_16x16x32_bf16(
                aF[ii][ks], bF[jn][ks], acc[ii][jn], 0, 0, 0);
      __builtin_amdgcn_s_setprio(0);
      asm volatile("" ::: "memory");
      __builtin_amdgcn_s_barrier();
    }
    // ===== phase 1: stage B_lo(kt+2) -> Bs[cur] =====
    PHASE(1,
          if (kt + 2 < NKT) { STGB(cur, kt + 2, 0); STGB(cur, kt + 2, 1); }, );
    // ===== phase 2: stage B_hi(kt+2) -> Bs[cur] =====
    PHASE(2,
          if (kt + 2 < NKT) { STGB(cur, kt + 2, 2); STGB(cur, kt + 2, 3); }, );
    // ===== phase 3: counted wait for next K-tile =====
    PHASE(3, ,
          if (kt + 2 < NKT) { asm volatile("s_waitcnt vmcnt(4)" ::: "memory"); }
          else if (kt + 1 < NKT) { asm volatile("s_waitcnt vmcnt(0)" ::: "memory"); });
  }
#undef STGA
#undef STGB
#undef PHASE

  // ---- epilogue via LDS: swizzled scatter, then coalesced 16B stores ----
  asm volatile("s_waitcnt lgkmcnt(0) vmcnt(0)" ::: "memory");
  __builtin_amdgcn_s_barrier();                   // all waves done with stage LDS

  const int q4 = (l >> 4) * 4;
  float bvj[4];
#pragma unroll
  for (int jn = 0; jn < 4; ++jn) {
    const int col = wn * 64 + jn * 16 + r;
    bvj[jn] = bias ? bias[bn * 256 + col] : 0.f;
  }
#pragma unroll
  for (int i = 0; i < MI; ++i) {
#pragma unroll
    for (int jn = 0; jn < 4; ++jn) {
      const int col = wn * 64 + jn * 16 + r;
      const int chunk = col >> 3;
#pragma unroll
      for (int q = 0; q < 4; ++q) {
        const int rowl = wm * (BM / 2) + i * 16 + q4 + q;
        const int pch = chunk ^ (rowl & 7);
        smem[rowl * 256 + pch * 8 + (col & 7)] = f2bf(acc[i][jn][q] + bvj[jn]);
      }
    }
  }
  __builtin_amdgcn_s_barrier();

  const int rrow0 = t >> 5;                       // 0..15
  const int rch = t & 31;                         // logical 16B chunk
#pragma unroll
  for (int p = 0; p < BM / 16; ++p) {
    const int rowl = p * 16 + rrow0;
    const int pch = rch ^ (rowl & 7);
    u16x8 vv = *(const u16x8*)&smem[rowl * 256 + pch * 8];
    const size_t grow = (size_t)(bm * BM + rowl);
    *(u16x8*)&C[grow * N + bn * 256 + rch * 8] = vv;
  }
}

// ---------------------------------------------------------------------------
// Scan kernels. lin[row, 2048] (bf16): [theta | retain_logit | inp_r | inp_i]
// cum_mag as running product (== exp(cumsum(log(clip(rt,1e-6)))) within fp32
// noise); the 1e-8 clip on the inverse is preserved exactly.
// ---------------------------------------------------------------------------
__global__ __launch_bounds__(256) void scan_k1(const ushort* __restrict__ lin,
                                               float4* __restrict__ agg) {
  int bd = blockIdx.x * 256 + threadIdx.x;    // 0..2047  (b*512 + d)
  int c  = blockIdx.y;                         // 0..127
  int b  = bd >> 9, d = bd & 511;
  const ushort* base = lin + ((size_t)b * 4096 + (size_t)c * 32) * 2048;
  float cth = 0.f, cbr = 0.f, cbi = 0.f;
  float cm = 1.f, cs = 1.f, sn = 0.f;
#pragma unroll 4
  for (int t = 0; t < 32; ++t) {
    const ushort* row = base + (size_t)t * 2048;
    float th = bf2f(row[d]);
    float z  = bf2f(row[512 + d]);
    float ir = bf2f(row[1024 + d]);
    float ii = bf2f(row[1536 + d]);
    float rt = __fdividef(1.f, 1.f + __expf(-z));
    cm *= fmaxf(rt, 1e-6f);
    cth += th;
    float s_, c_;
    __sincosf(cth, &s_, &c_);
    float im = __fdividef(1.f, fmaxf(cm, 1e-8f));
    float invr = im * c_, invi = -im * s_;
    float drive = 1.f - rt;
    float br_ = drive * ir, bi_ = drive * ii;
    cbr += invr * br_ - invi * bi_;
    cbi += invr * bi_ + invi * br_;
    cs = c_; sn = s_;
  }
  agg[(size_t)c * 2048 + bd] = make_float4(cm * cs, cm * sn, cbr, cbi);
}

__global__ __launch_bounds__(256) void scan_k2(const float4* __restrict__ agg,
                                               float2* __restrict__ h0) {
  int bd = blockIdx.x * 256 + threadIdx.x;    // 2048 threads
  float hr = 0.f, hi = 0.f;
  for (int cg = 0; cg < 16; ++cg) {
    float4 a[8];
#pragma unroll
    for (int u = 0; u < 8; ++u) a[u] = agg[(size_t)(cg * 8 + u) * 2048 + bd];
#pragma unroll
    for (int u = 0; u < 8; ++u) {
      h0[(size_t)(cg * 8 + u) * 2048 + bd] = make_float2(hr, hi);
      float tr = hr + a[u].z, ti = hi + a[u].w;
      hr = a[u].x * tr - a[u].y * ti;
      hi = a[u].x * ti + a[u].y * tr;
    }
  }
}

__global__ __launch_bounds__(256) void scan_k3(const ushort* __restrict__ lin,
                                               const float2* __restrict__ h0,
                                               ushort* __restrict__ outb) {
  int bd = blockIdx.x * 256 + threadIdx.x;
  int c  = blockIdx.y;
  int b  = bd >> 9, d = bd & 511;
  const ushort* base = lin + ((size_t)b * 4096 + (size_t)c * 32) * 2048;
  float2 h = h0[(size_t)c * 2048 + bd];
  float cth = 0.f, cbr = 0.f, cbi = 0.f, cm = 1.f;
#pragma unroll 4
  for (int t = 0; t < 32; ++t) {
    const ushort* row = base + (size_t)t * 2048;
    float th = bf2f(row[d]);
    float z  = bf2f(row[512 + d]);
    float ir = bf2f(row[1024 + d]);
    float ii = bf2f(row[1536 + d]);
    float rt = __fdividef(1.f, 1.f + __expf(-z));
    cm *= fmaxf(rt, 1e-6f);
    cth += th;
    float s_, c_;
    __sincosf(cth, &s_, &c_);
    float im = __fdividef(1.f, fmaxf(cm, 1e-8f));
    float invr = im * c_, invi = -im * s_;
    float drive = 1.f - rt;
    float br_ = drive * ir, bi_ = drive * ii;
    cbr += invr * br_ - invi * bi_;
    cbi += invr * bi_ + invi * br_;
    float ar = cm * c_, ai = cm * s_;
    float tr = h.x + cbr, ti = h.y + cbi;
    float orr = ar * tr - ai * ti;
    float oii = ar * ti + ai * tr;
    size_t rowo = ((size_t)b * 4096 + (size_t)c * 32 + t) * 1024;
    outb[rowo + d] = f2bf(orr);
    outb[rowo + 512 + d] = f2bf(oii);
  }
}

// ---------------------------------------------------------------------------
// LayerNorm over D=1024, one block per row; y = yb + xb (residual fused here).
// ---------------------------------------------------------------------------
__global__ __launch_bounds__(256) void ln_k(const ushort* __restrict__ yb,
                                            const ushort* __restrict__ xb,
                                            const float* __restrict__ gamma,
                                            const float* __restrict__ beta,
                                            float* __restrict__ out) {
  int row = blockIdx.x;
  ushort4 uy = ((const ushort4*)(yb + (size_t)row * 1024))[threadIdx.x];
  ushort4 ux = ((const ushort4*)(xb + (size_t)row * 1024))[threadIdx.x];
  float4 v;
  v.x = bf2f(uy.x) + bf2f(ux.x);
  v.y = bf2f(uy.y) + bf2f(ux.y);
  v.z = bf2f(uy.z) + bf2f(ux.z);
  v.w = bf2f(uy.w) + bf2f(ux.w);
  float s  = v.x + v.y + v.z + v.w;
  float s2 = v.x * v.x + v.y * v.y + v.z * v.z + v.w * v.w;
#pragma unroll
  for (int off = 32; off > 0; off >>= 1) {
    s  += __shfl_down(s, off);
    s2 += __shfl_down(s2, off);
  }
  __shared__ float red[8];
  __shared__ float mv[2];
  int l = threadIdx.x & 63, w = threadIdx.x >> 6;
  if (l == 0) { red[w] = s; red[4 + w] = s2; }
  __syncthreads();
  if (threadIdx.x == 0) {
    float ts = red[0] + red[1] + red[2] + red[3];
    float t2 = red[4] + red[5] + red[6] + red[7];
    float mu = ts * (1.f / 1024.f);
    float var = t2 * (1.f / 1024.f) - mu * mu;
    mv[0] = mu;
    mv[1] = 1.f / sqrtf(var + 1e-5f);
  }
  __syncthreads();
  float mu = mv[0], rstd = mv[1];
  const float4* g4 = (const float4*)gamma;
  const float4* b4 = (const float4*)beta;
  float4 gv = g4[threadIdx.x], bv = b4[threadIdx.x];
  float4 o;
  o.x = (v.x - mu) * rstd * gv.x + bv.x;
  o.y = (v.y - mu) * rstd * gv.y + bv.y;
  o.z = (v.z - mu) * rstd * gv.z + bv.z;
  o.w = (v.w - mu) * rstd * gv.w + bv.w;
  ((float4*)(out + (size_t)row * 1024))[threadIdx.x] = o;
}

// ---------------------------------------------------------------------------
extern "C" void kernel_launch(void* const* d_in, const int* in_sizes, int n_in,
                              void* d_out, int out_size, void* d_ws, size_t ws_size,
                              hipStream_t stream) {
  (void)in_sizes; (void)n_in; (void)out_size; (void)ws_size;
  const float* x  = (const float*)d_in[0];
  const float* Wt = (const float*)d_in[1];
  const float* bt = (const float*)d_in[2];
  const float* Wr = (const float*)d_in[3];
  const float* br = (const float*)d_in[4];
  const float* Wi = (const float*)d_in[5];
  const float* bi = (const float*)d_in[6];
  const float* Wo = (const float*)d_in[7];
  const float* bo = (const float*)d_in[8];
  const float* gamma = (const float*)d_in[9];
  const float* beta  = (const float*)d_in[10];

  char* ws = (char*)d_ws;
  ushort* wcat_t = (ushort*)(ws);                      //  4 MiB: [2048][1024] bf16
  ushort* wo_t   = (ushort*)(ws + ((size_t)4  << 20)); //  2 MiB: [1024][1024] bf16
  float*  bcat   = (float*) (ws + ((size_t)6  << 20)); //  8 KiB
  float4* agg    = (float4*)(ws + ((size_t)8  << 20)); //  4 MiB: [128][2048]
  float2* h0     = (float2*)(ws + ((size_t)12 << 20)); //  2 MiB: [128][2048]
  ushort* xb     = (ushort*)(ws + ((size_t)16 << 20)); // 32 MiB: x bf16 (alive thru ln_k)
  ushort* outb   = (ushort*)(ws + ((size_t)48 << 20)); // 32 MiB: scan out bf16
  ushort* linb   = (ushort*)(ws + ((size_t)80 << 20)); // 64 MiB: lin bf16
  ushort* yb     = (ushort*)(ws + ((size_t)80 << 20)); // 32 MiB: y bf16 (overlays dead linb)

  // weight prep
  tconv<<<dim3(512 / 32, 1024 / 32), dim3(32, 8), 0, stream>>>(Wt, 1024, 512, wcat_t, 0);
  tconv<<<dim3(512 / 32, 1024 / 32), dim3(32, 8), 0, stream>>>(Wr, 1024, 512, wcat_t, 512);
  tconv<<<dim3(1024 / 32, 1024 / 32), dim3(32, 8), 0, stream>>>(Wi, 1024, 1024, wcat_t, 1024);
  tconv<<<dim3(1024 / 32, 1024 / 32), dim3(32, 8), 0, stream>>>(Wo, 1024, 1024, wo_t, 0);
  pack_bias<<<8, 256, 0, stream>>>(bt, br, bi, bcat);
  xconv<<<16384, 256, 0, stream>>>((const float4*)x, xb, 4194304);

  // lin(bf16) = x @ [Wt|Wr|Wi] + [bt|br|bi]   (M=16384 N=2048 K=1024, 512 blocks)
  gemm256<256><<<512, 512, 0, stream>>>(xb, wcat_t, linb, bcat, 16384, 2048, 1024, 8);

  // chunked complex scan
  scan_k1<<<dim3(8, 128), 256, 0, stream>>>(linb, agg);
  scan_k2<<<8, 256, 0, stream>>>(agg, h0);
  scan_k3<<<dim3(8, 128), 256, 0, stream>>>(linb, h0, outb);

  // yb(bf16) = out @ Wo + bo   (M=16384 N=1024 K=1024, 512 blocks of 128x256)
  gemm256<128><<<512, 512, 0, stream>>>(outb, wo_t, yb, bo, 16384, 1024, 1024, 4);

  // layernorm(yb + xb) -> d_out
  ln_k<<<16384, 256, 0, stream>>>(yb, xb, gamma, beta, (float*)d_out);
}